// Round 3
// baseline (234.251 us; speedup 1.0000x reference)
//
#include <hip/hip_runtime.h>
#include <math.h>

// ExplaiNN fused forward: B=128, N=300, L=600, K=19, C1=100, PS=7
// LC=582, LP=83, NC=2
#define EPS_ 1e-5f

// force a uniform float value into an SGPR
__device__ __forceinline__ float rfl(float v) {
    return __int_as_float(__builtin_amdgcn_readfirstlane(__float_as_int(v)));
}

// ---------------------------------------------------------------------------
// kT: transpose x[b][c][t] -> xT[c][t][b]   (1.2 MB, trivial)
// grid (30, 4): t-tile of 20 per block, c = blockIdx.y. 256 threads.
// ---------------------------------------------------------------------------
__global__ __launch_bounds__(256) void kT(const float* __restrict__ x,
                                          float* __restrict__ xT) {
    __shared__ float sX[128 * 25];          // stride 25 (odd) -> conflict-free
    const int tid = threadIdx.x;
    const int t0  = blockIdx.x * 20;
    const int c   = blockIdx.y;
    for (int i = tid; i < 128 * 5; i += 256) {   // 5 float4 per b
        const int b = i / 5, f = i % 5;
        const float4 v = *reinterpret_cast<const float4*>(
            x + b * 2400 + c * 600 + t0 + 4 * f);
        sX[b * 25 + 4 * f + 0] = v.x;
        sX[b * 25 + 4 * f + 1] = v.y;
        sX[b * 25 + 4 * f + 2] = v.z;
        sX[b * 25 + 4 * f + 3] = v.w;
    }
    __syncthreads();
    for (int j = tid; j < 20 * 128; j += 256) {
        const int tt = j >> 7, b = j & 127;
        xT[(c * 600 + t0 + tt) * 128 + b] = sX[b * 25 + tt];
    }
}

// ---------------------------------------------------------------------------
// kA: conv1d(4ch,K=19) + bias + bn1 + exp + maxpool(7,7).  NO LDS.
// grid 2400 x 64 threads: block = one wave = (n, b-half, p-range).
// lane = b. Weights wave-uniform -> SGPRs. x from xT, coalesced 256B loads,
// 25-deep sliding register window per channel (shift 7 per pooled output).
// Output pooled[n][p][b] (coalesced store, coalesced kB load).
// ---------------------------------------------------------------------------
__global__ __launch_bounds__(64, 3) void kA(
        const float* __restrict__ xT,       // [4][600][128]
        const float* __restrict__ conv_w,   // [300][4][19]
        const float* __restrict__ conv_b,
        const float* __restrict__ g1, const float* __restrict__ b1,
        const float* __restrict__ m1, const float* __restrict__ v1,
        float* __restrict__ pooled)         // [300][83][128]
{
    const int wid = blockIdx.x;             // 0..2399
    const int n   = wid >> 3;
    const int r   = wid & 7;
    const int bh  = r >> 2;                 // b-half
    const int pr  = r & 3;                  // p-range
    const int p0  = pr * 21;
    const int np  = (pr < 3) ? 21 : 20;     // 83 = 21+21+21+20
    const int bb  = bh * 64 + threadIdx.x;

    // wave-uniform weights -> SGPRs
    float w[4][19];
    #pragma unroll
    for (int c = 0; c < 4; ++c)
        #pragma unroll
        for (int k = 0; k < 19; ++k)
            w[c][k] = rfl(conv_w[n * 76 + c * 19 + k]);

    const float A1 = rfl(g1[n]) * rsqrtf(rfl(v1[n]) + EPS_);
    const float B1 = A1 * (rfl(conv_b[n]) - rfl(m1[n])) + rfl(b1[n]);

    const float* xb = xT + bb;              // lane base
    float win[4][25];
    {
        const float* px = xb + (7 * p0) * 128;
        #pragma unroll
        for (int c = 0; c < 4; ++c)
            #pragma unroll
            for (int j = 0; j < 18; ++j)
                win[c][j] = px[(c * 600 + j) * 128];
    }

    float* outp = pooled + (n * 83 + p0) * 128 + bb;
    for (int p = 0; p < np; ++p) {
        const float* px = xb + 7 * (p0 + p) * 128;
        #pragma unroll
        for (int c = 0; c < 4; ++c)
            #pragma unroll
            for (int j = 18; j < 25; ++j)
                win[c][j] = px[(c * 600 + j) * 128];

        float acc[7];
        #pragma unroll
        for (int q = 0; q < 7; ++q) acc[q] = 0.f;
        #pragma unroll
        for (int c = 0; c < 4; ++c)
            #pragma unroll
            for (int k = 0; k < 19; ++k) {
                const float wv = w[c][k];
                #pragma unroll
                for (int q = 0; q < 7; ++q)
                    acc[q] = fmaf(win[c][k + q], wv, acc[q]);
            }
        float mx = -INFINITY;               // exp monotone: max before exp
        #pragma unroll
        for (int q = 0; q < 7; ++q) mx = fmaxf(mx, fmaf(A1, acc[q], B1));
        outp[p * 128] = __expf(mx);

        #pragma unroll
        for (int c = 0; c < 4; ++c)
            #pragma unroll
            for (int j = 0; j < 18; ++j)
                win[c][j] = win[c][j + 7];
    }
}

// ---------------------------------------------------------------------------
// kB: fc1(K=83) + bn2 + relu + fc2 + bn3 + relu.
// grid 600 x 256: block = (n, b-half), 4 waves = 4 h-groups of 25.
// lane = b. All weights/params wave-uniform -> scalar loads. pv chunked in
// registers (compile-time indexed). LDS only for the 4x64 hg-reduction.
// ---------------------------------------------------------------------------
__global__ __launch_bounds__(256) void kB(
        const float* __restrict__ pooled,   // [300][83][128]
        const float* __restrict__ fc1w,     // [300][100][83]
        const float* __restrict__ fc1b,     // [300][100]
        const float* __restrict__ g2, const float* __restrict__ b2,
        const float* __restrict__ m2, const float* __restrict__ v2,
        const float* __restrict__ fc2w,     // [300][100]
        const float* __restrict__ fc2b,     // [300]
        const float* __restrict__ g3, const float* __restrict__ b3,
        const float* __restrict__ m3, const float* __restrict__ v3,
        float* __restrict__ sout)           // [300][128]
{
    __shared__ float sRed[4][64];
    const int blk  = blockIdx.x;            // 0..599
    const int n    = blk >> 1;
    const int bh   = blk & 1;
    const int tid  = threadIdx.x;
    const int lane = tid & 63;
    const int hg   = __builtin_amdgcn_readfirstlane(tid >> 6);  // wave id
    const int h0   = hg * 25;
    const int bb   = bh * 64 + lane;

    const float* pvb  = pooled + (n * 83) * 128 + bb;
    const float* wrow = fc1w + (size_t)n * 8300 + h0 * 83;

    float acc[25];
    #pragma unroll
    for (int j = 0; j < 25; ++j) acc[j] = 0.f;

    for (int k0 = 0; k0 < 80; k0 += 16) {
        float pv[16];
        #pragma unroll
        for (int kk = 0; kk < 16; ++kk) pv[kk] = pvb[(k0 + kk) * 128];
        #pragma unroll
        for (int j = 0; j < 25; ++j) {
            #pragma unroll
            for (int kk = 0; kk < 16; ++kk) {
                const float wv = rfl(wrow[j * 83 + k0 + kk]);
                acc[j] = fmaf(pv[kk], wv, acc[j]);
            }
        }
    }
    {   // tail k = 80..82
        float pv[3];
        #pragma unroll
        for (int kk = 0; kk < 3; ++kk) pv[kk] = pvb[(80 + kk) * 128];
        #pragma unroll
        for (int j = 0; j < 25; ++j) {
            #pragma unroll
            for (int kk = 0; kk < 3; ++kk) {
                const float wv = rfl(wrow[j * 83 + 80 + kk]);
                acc[j] = fmaf(pv[kk], wv, acc[j]);
            }
        }
    }

    // bn2 + relu + fc2 partial (params uniform -> scalar loads)
    float part = 0.f;
    #pragma unroll
    for (int j = 0; j < 25; ++j) {
        const int i = n * 100 + h0 + j;
        const float A2 = rfl(g2[i]) * rsqrtf(rfl(v2[i]) + EPS_);
        const float C2 = fmaf(A2, rfl(fc1b[i]) - rfl(m2[i]), rfl(b2[i]));
        const float act = fmaxf(fmaf(A2, acc[j], C2), 0.f);
        part = fmaf(act, rfl(fc2w[i]), part);
    }
    sRed[hg][lane] = part;
    __syncthreads();
    if (tid < 64) {
        float s = sRed[0][lane] + sRed[1][lane] + sRed[2][lane] + sRed[3][lane];
        s += fc2b[n];
        const float A3 = g3[n] * rsqrtf(v3[n] + EPS_);
        const float z = fmaf(A3, s - m3[n], b3[n]);
        sout[n * 128 + bb] = fmaxf(z, 0.f);
    }
}

// ---------------------------------------------------------------------------
// kC: out[b,c] = sum_n sout[n][b] * fw[c][n] + fb[c].  grid 128 x 64.
// ---------------------------------------------------------------------------
__global__ __launch_bounds__(64) void kC(
        const float* __restrict__ sout,     // [300][128]
        const float* __restrict__ fw,       // [2][300]
        const float* __restrict__ fb,
        float* __restrict__ out)            // [128][2]
{
    const int b = blockIdx.x, t = threadIdx.x;
    float a0 = 0.f, a1 = 0.f;
    for (int nn = t; nn < 300; nn += 64) {
        const float v = sout[nn * 128 + b];
        a0 = fmaf(v, fw[nn], a0);
        a1 = fmaf(v, fw[300 + nn], a1);
    }
    #pragma unroll
    for (int off = 32; off > 0; off >>= 1) {
        a0 += __shfl_xor(a0, off, 64);
        a1 += __shfl_xor(a1, off, 64);
    }
    if (t == 0) {
        out[b * 2 + 0] = a0 + fb[0];
        out[b * 2 + 1] = a1 + fb[1];
    }
}

extern "C" void kernel_launch(void* const* d_in, const int* in_sizes, int n_in,
                              void* d_out, int out_size, void* d_ws, size_t ws_size,
                              hipStream_t stream) {
    const float* x      = (const float*)d_in[0];
    const float* conv_w = (const float*)d_in[1];
    const float* conv_b = (const float*)d_in[2];
    const float* g1 = (const float*)d_in[3];
    const float* b1 = (const float*)d_in[4];
    const float* m1 = (const float*)d_in[5];
    const float* v1 = (const float*)d_in[6];
    const float* fc1_w = (const float*)d_in[7];
    const float* fc1_b = (const float*)d_in[8];
    const float* g2 = (const float*)d_in[9];
    const float* b2 = (const float*)d_in[10];
    const float* m2 = (const float*)d_in[11];
    const float* v2 = (const float*)d_in[12];
    const float* fc2_w = (const float*)d_in[13];
    const float* fc2_b = (const float*)d_in[14];
    const float* g3 = (const float*)d_in[15];
    const float* b3 = (const float*)d_in[16];
    const float* m3 = (const float*)d_in[17];
    const float* v3 = (const float*)d_in[18];
    const float* fw = (const float*)d_in[19];
    const float* fb = (const float*)d_in[20];
    float* out = (float*)d_out;

    float* xT     = (float*)d_ws;                        // 4*600*128   = 307200
    float* pooled = xT + 307200;                         // 300*83*128  = 3187200
    float* sout   = pooled + (size_t)300 * 83 * 128;     // 300*128     = 38400
    // total ws: 14.13 MB

    kT<<<dim3(30, 4), 256, 0, stream>>>(x, xT);
    kA<<<2400, 64, 0, stream>>>(xT, conv_w, conv_b, g1, b1, m1, v1, pooled);
    kB<<<600, 256, 0, stream>>>(pooled, fc1_w, fc1_b, g2, b2, m2, v2,
                                fc2_w, fc2_b, g3, b3, m3, v3, sout);
    kC<<<128, 64, 0, stream>>>(sout, fw, fb, out);
}

// Round 4
// 232.152 us; speedup vs baseline: 1.0090x; 1.0090x over previous
//
#include <hip/hip_runtime.h>
#include <math.h>

// ExplaiNN fused forward: B=128, N=300, L=600, K=19, C1=100, PS=7
// LC=582, LP=83, NC=2
#define EPS_ 1e-5f

// force a uniform float value into an SGPR (use ONLY for few, hot-reused values)
__device__ __forceinline__ float rfl(float v) {
    return __int_as_float(__builtin_amdgcn_readfirstlane(__float_as_int(v)));
}

// ---------------------------------------------------------------------------
// kT: transpose x[b][c][t] -> xT[c][t][b]   (1.2 MB, trivial)
// grid (30, 4): t-tile of 20 per block, c = blockIdx.y. 256 threads.
// ---------------------------------------------------------------------------
__global__ __launch_bounds__(256) void kT(const float* __restrict__ x,
                                          float* __restrict__ xT) {
    __shared__ float sX[128 * 25];          // stride 25 (odd) -> conflict-free
    const int tid = threadIdx.x;
    const int t0  = blockIdx.x * 20;
    const int c   = blockIdx.y;
    for (int i = tid; i < 128 * 5; i += 256) {   // 5 float4 per b
        const int b = i / 5, f = i % 5;
        const float4 v = *reinterpret_cast<const float4*>(
            x + b * 2400 + c * 600 + t0 + 4 * f);
        sX[b * 25 + 4 * f + 0] = v.x;
        sX[b * 25 + 4 * f + 1] = v.y;
        sX[b * 25 + 4 * f + 2] = v.z;
        sX[b * 25 + 4 * f + 3] = v.w;
    }
    __syncthreads();
    for (int j = tid; j < 20 * 128; j += 256) {
        const int tt = j >> 7, b = j & 127;
        xT[(c * 600 + t0 + tt) * 128 + b] = sX[b * 25 + tt];
    }
}

// ---------------------------------------------------------------------------
// kA: conv1d(4ch,K=19) + bias + bn1 + exp + maxpool(7,7).  NO LDS, no carried
// state. grid 4800 x 64: wave = (n, b-half, p-chunk of ~10). lane = b.
// Per p: load 25 x-values per channel FRESH (live set 25+7 regs -> matches
// the allocator's preference, no remat), 532 FMAs. Weights wave-uniform in
// SGPRs. Consecutive p overlap 72% in L1. Output pooled[n][p][b].
// ---------------------------------------------------------------------------
__global__ __launch_bounds__(64) void kA(
        const float* __restrict__ xT,       // [4][600][128]
        const float* __restrict__ conv_w,   // [300][4][19]
        const float* __restrict__ conv_b,
        const float* __restrict__ g1, const float* __restrict__ b1,
        const float* __restrict__ m1, const float* __restrict__ v1,
        float* __restrict__ pooled)         // [300][83][128]
{
    const int wid = blockIdx.x;             // 0..4799
    const int n   = wid >> 4;
    const int sub = wid & 15;
    const int bh  = sub & 1;
    const int r   = sub >> 1;               // 0..7 p-chunk
    const int p0  = (r * 83) >> 3;
    const int p1  = ((r + 1) * 83) >> 3;    // chunks of 10/11
    const int bb  = bh * 64 + threadIdx.x;

    // wave-uniform weights -> SGPRs (76 values, each reused ~70x)
    float w[4][19];
    #pragma unroll
    for (int c = 0; c < 4; ++c)
        #pragma unroll
        for (int k = 0; k < 19; ++k)
            w[c][k] = rfl(conv_w[n * 76 + c * 19 + k]);

    const float A1 = rfl(g1[n]) * rsqrtf(rfl(v1[n]) + EPS_);
    const float B1 = A1 * (rfl(conv_b[n]) - rfl(m1[n])) + rfl(b1[n]);

    const float* xb   = xT + bb;
    float*       outp = pooled + (n * 83) * 128 + bb;

    for (int p = p0; p < p1; ++p) {
        const int t0 = 7 * p;
        float acc[7];
        #pragma unroll
        for (int q = 0; q < 7; ++q) acc[q] = 0.f;

        #pragma unroll
        for (int c = 0; c < 4; ++c) {
            float xv[25];
            #pragma unroll
            for (int j = 0; j < 25; ++j)
                xv[j] = xb[(c * 600 + t0 + j) * 128];
            #pragma unroll
            for (int k = 0; k < 19; ++k) {
                const float wv = w[c][k];
                #pragma unroll
                for (int q = 0; q < 7; ++q)
                    acc[q] = fmaf(xv[k + q], wv, acc[q]);
            }
        }
        float mx = -INFINITY;               // exp monotone: max before exp
        #pragma unroll
        for (int q = 0; q < 7; ++q) mx = fmaxf(mx, fmaf(A1, acc[q], B1));
        outp[p * 128] = __expf(mx);
    }
}

// ---------------------------------------------------------------------------
// kB: fc1(K=83) + bn2 + relu + fc2 + bn3 + relu.
// grid 600 x 256: block = (n, b-half), 4 waves = 4 h-groups of 25. lane = b.
// Weight/param addresses are wave-uniform (blockIdx + readfirstlane'd wave
// id) -> uniformity analysis emits vectorized s_load; NO per-element rfl.
// LDS only for the 4x64 hg-reduction.
// ---------------------------------------------------------------------------
__global__ __launch_bounds__(256) void kB(
        const float* __restrict__ pooled,   // [300][83][128]
        const float* __restrict__ fc1w,     // [300][100][83]
        const float* __restrict__ fc1b,     // [300][100]
        const float* __restrict__ g2, const float* __restrict__ b2,
        const float* __restrict__ m2, const float* __restrict__ v2,
        const float* __restrict__ fc2w,     // [300][100]
        const float* __restrict__ fc2b,     // [300]
        const float* __restrict__ g3, const float* __restrict__ b3,
        const float* __restrict__ m3, const float* __restrict__ v3,
        float* __restrict__ sout)           // [300][128]
{
    __shared__ float sRed[4][64];
    const int blk  = blockIdx.x;            // 0..599
    const int n    = blk >> 1;
    const int bh   = blk & 1;
    const int tid  = threadIdx.x;
    const int lane = tid & 63;
    const int hg   = __builtin_amdgcn_readfirstlane(tid >> 6);  // wave id
    const int h0   = hg * 25;
    const int bb   = bh * 64 + lane;

    const float* pvb  = pooled + (n * 83) * 128 + bb;
    const float* wrow = fc1w + (size_t)n * 8300 + h0 * 83;      // uniform

    float acc[25];
    #pragma unroll
    for (int j = 0; j < 25; ++j) acc[j] = 0.f;

    for (int k0 = 0; k0 < 80; k0 += 16) {
        float pv[16];
        #pragma unroll
        for (int kk = 0; kk < 16; ++kk) pv[kk] = pvb[(k0 + kk) * 128];
        #pragma unroll
        for (int j = 0; j < 25; ++j) {
            #pragma unroll
            for (int kk = 0; kk < 16; ++kk)
                acc[j] = fmaf(pv[kk], wrow[j * 83 + k0 + kk], acc[j]);
        }
    }
    {   // tail k = 80..82
        float pv[3];
        #pragma unroll
        for (int kk = 0; kk < 3; ++kk) pv[kk] = pvb[(80 + kk) * 128];
        #pragma unroll
        for (int j = 0; j < 25; ++j) {
            #pragma unroll
            for (int kk = 0; kk < 3; ++kk)
                acc[j] = fmaf(pv[kk], wrow[j * 83 + 80 + kk], acc[j]);
        }
    }

    // bn2 + relu + fc2 partial (all params at uniform addresses -> s_load)
    const float* pg2 = g2 + n * 100 + h0;
    const float* pb2 = b2 + n * 100 + h0;
    const float* pm2 = m2 + n * 100 + h0;
    const float* pv2 = v2 + n * 100 + h0;
    const float* pfb = fc1b + n * 100 + h0;
    const float* pw2 = fc2w + n * 100 + h0;
    float part = 0.f;
    #pragma unroll
    for (int j = 0; j < 25; ++j) {
        const float A2 = pg2[j] * rsqrtf(pv2[j] + EPS_);
        const float C2 = fmaf(A2, pfb[j] - pm2[j], pb2[j]);
        const float act = fmaxf(fmaf(A2, acc[j], C2), 0.f);
        part = fmaf(act, pw2[j], part);
    }
    sRed[hg][lane] = part;
    __syncthreads();
    if (tid < 64) {
        float s = sRed[0][lane] + sRed[1][lane] + sRed[2][lane] + sRed[3][lane];
        s += fc2b[n];
        const float A3 = g3[n] * rsqrtf(v3[n] + EPS_);
        const float z = fmaf(A3, s - m3[n], b3[n]);
        sout[n * 128 + bb] = fmaxf(z, 0.f);
    }
}

// ---------------------------------------------------------------------------
// kC: out[b,c] = sum_n sout[n][b] * fw[c][n] + fb[c].  grid 128 x 64.
// ---------------------------------------------------------------------------
__global__ __launch_bounds__(64) void kC(
        const float* __restrict__ sout,     // [300][128]
        const float* __restrict__ fw,       // [2][300]
        const float* __restrict__ fb,
        float* __restrict__ out)            // [128][2]
{
    const int b = blockIdx.x, t = threadIdx.x;
    float a0 = 0.f, a1 = 0.f;
    for (int nn = t; nn < 300; nn += 64) {
        const float v = sout[nn * 128 + b];
        a0 = fmaf(v, fw[nn], a0);
        a1 = fmaf(v, fw[300 + nn], a1);
    }
    #pragma unroll
    for (int off = 32; off > 0; off >>= 1) {
        a0 += __shfl_xor(a0, off, 64);
        a1 += __shfl_xor(a1, off, 64);
    }
    if (t == 0) {
        out[b * 2 + 0] = a0 + fb[0];
        out[b * 2 + 1] = a1 + fb[1];
    }
}

extern "C" void kernel_launch(void* const* d_in, const int* in_sizes, int n_in,
                              void* d_out, int out_size, void* d_ws, size_t ws_size,
                              hipStream_t stream) {
    const float* x      = (const float*)d_in[0];
    const float* conv_w = (const float*)d_in[1];
    const float* conv_b = (const float*)d_in[2];
    const float* g1 = (const float*)d_in[3];
    const float* b1 = (const float*)d_in[4];
    const float* m1 = (const float*)d_in[5];
    const float* v1 = (const float*)d_in[6];
    const float* fc1_w = (const float*)d_in[7];
    const float* fc1_b = (const float*)d_in[8];
    const float* g2 = (const float*)d_in[9];
    const float* b2 = (const float*)d_in[10];
    const float* m2 = (const float*)d_in[11];
    const float* v2 = (const float*)d_in[12];
    const float* fc2_w = (const float*)d_in[13];
    const float* fc2_b = (const float*)d_in[14];
    const float* g3 = (const float*)d_in[15];
    const float* b3 = (const float*)d_in[16];
    const float* m3 = (const float*)d_in[17];
    const float* v3 = (const float*)d_in[18];
    const float* fw = (const float*)d_in[19];
    const float* fb = (const float*)d_in[20];
    float* out = (float*)d_out;

    float* xT     = (float*)d_ws;                        // 4*600*128   = 307200
    float* pooled = xT + 307200;                         // 300*83*128  = 3187200
    float* sout   = pooled + (size_t)300 * 83 * 128;     // 300*128     = 38400
    // total ws: 14.13 MB

    kT<<<dim3(30, 4), 256, 0, stream>>>(x, xT);
    kA<<<4800, 64, 0, stream>>>(xT, conv_w, conv_b, g1, b1, m1, v1, pooled);
    kB<<<600, 256, 0, stream>>>(pooled, fc1_w, fc1_b, g2, b2, m2, v2,
                                fc2_w, fc2_b, g3, b3, m3, v3, sout);
    kC<<<128, 64, 0, stream>>>(sout, fw, fb, out);
}

// Round 5
// 198.922 us; speedup vs baseline: 1.1776x; 1.1671x over previous
//
#include <hip/hip_runtime.h>
#include <math.h>

// ExplaiNN fused forward: B=128, N=300, L=600, K=19, C1=100, PS=7
// LC=582, LP=83, NC=2
#define EPS_ 1e-5f

// ---------------------------------------------------------------------------
// kP: transposes. Blocks 0..299: fc1_w[n][h][p] -> w1T[n][p][h] (per-n LDS
// transpose, pad 101 -> conflict-free). Block 300: conv_w[n][c*19+k] ->
// cwT[c*19+k][n] (91 KB LDS stage).
// ---------------------------------------------------------------------------
__global__ __launch_bounds__(256) void kP(const float* __restrict__ fc1w,
                                          const float* __restrict__ conv_w,
                                          float* __restrict__ w1T,
                                          float* __restrict__ cwT) {
    __shared__ float sm[22800];
    const int blk = blockIdx.x, tid = threadIdx.x;
    if (blk < 300) {
        // stage transposed: sm[p*101+h] = fc1w[n][h][p]
        for (int i = tid; i < 8300; i += 256) {
            const int h = i / 83, p = i - h * 83;
            sm[p * 101 + h] = fc1w[(size_t)blk * 8300 + i];
        }
        __syncthreads();
        for (int i = tid; i < 8300; i += 256) {
            const int p = i / 100, h = i - p * 100;
            w1T[(size_t)blk * 8300 + i] = sm[p * 101 + h];
        }
    } else {
        for (int i = tid; i < 22800; i += 256) sm[i] = conv_w[i];
        __syncthreads();
        for (int i = tid; i < 22800; i += 256) {
            const int k = i / 300, n = i - k * 300;
            cwT[i] = sm[n * 76 + k];
        }
    }
}

// ---------------------------------------------------------------------------
// kA: conv1d(4ch,K=19) + bias + bn1 + exp + maxpool(7,7).
// grid 5120 x 64: block id = b*40 + ng*8 + pc  (40%8==0 -> all b of one
// (ng,pc) group land on the SAME XCD -> pooled lines assemble in local L2).
// lane = n (ng*64+lane). Weights PER-LANE in VGPRs (76, coalesced from cwT).
// x is WAVE-UNIFORM -> s_load from original x[b][c][t] (contiguous rows);
// inner loop is pure v_fmac_f32 v,s,v - no vector loads, no addr math.
// Store pooled[n][p][b]: per-lane scatter (3.4M dwords total, ~1-2us).
// ---------------------------------------------------------------------------
__global__ __launch_bounds__(64) void kA(
        const float* __restrict__ x,        // [128][4][600]
        const float* __restrict__ cwT,      // [76][300]
        const float* __restrict__ conv_b,
        const float* __restrict__ g1, const float* __restrict__ b1,
        const float* __restrict__ m1, const float* __restrict__ v1,
        float* __restrict__ pooled)         // [300][83][128]
{
    const int id  = blockIdx.x;             // 0..5119
    const int b   = id / 40;
    const int sub = id - b * 40;
    const int ng  = sub >> 3;
    const int pc  = sub & 7;
    const int p0  = (pc * 83) >> 3;
    const int p1  = ((pc + 1) * 83) >> 3;   // chunks of 10/11
    const int lane = threadIdx.x;
    const int n   = ng * 64 + lane;
    const int nc  = (n < 300) ? n : 299;

    // per-lane weights: 76 coalesced loads, reused over ~10 p-tasks
    float w[4][19];
    #pragma unroll
    for (int c = 0; c < 4; ++c)
        #pragma unroll
        for (int k = 0; k < 19; ++k)
            w[c][k] = cwT[(c * 19 + k) * 300 + nc];

    const float A1 = g1[nc] * rsqrtf(v1[nc] + EPS_);
    const float B1 = fmaf(A1, conv_b[nc] - m1[nc], b1[nc]);

    const float* xb = x + b * 2400;         // wave-uniform base

    for (int p = p0; p < p1; ++p) {
        const int t0 = 7 * p;
        float acc[7];
        #pragma unroll
        for (int q = 0; q < 7; ++q) acc[q] = 0.f;

        #pragma unroll
        for (int c = 0; c < 4; ++c) {
            const float* xc = xb + c * 600 + t0;   // uniform -> s_load
            float xv[25];
            #pragma unroll
            for (int j = 0; j < 25; ++j) xv[j] = xc[j];
            #pragma unroll
            for (int k = 0; k < 19; ++k) {
                const float wv = w[c][k];
                #pragma unroll
                for (int q = 0; q < 7; ++q)
                    acc[q] = fmaf(xv[k + q], wv, acc[q]);   // v,s,v
            }
        }
        float mx = -INFINITY;               // exp monotone: max before exp
        #pragma unroll
        for (int q = 0; q < 7; ++q) mx = fmaxf(mx, fmaf(A1, acc[q], B1));
        if (n < 300)
            pooled[((size_t)n * 83 + p) * 128 + b] = __expf(mx);
    }
}

// ---------------------------------------------------------------------------
// kB: fc1(K=83) + bn2 + relu + fc2 + bn3 + relu.
// grid 2432 x 128: id = bc*304 + n (304%8==0 -> all 8 b-chunks of one n on
// the same XCD -> w1T L2-resident). 2 waves: h = hw*50 + lane (lane<50).
// lane = h: w1T loads coalesced VECTOR; pooled (16 b) via aligned
// s_load_dwordx4. acc[16] per lane; fc2 = 64-lane butterfly per acc.
// ---------------------------------------------------------------------------
__global__ __launch_bounds__(128) void kB(
        const float* __restrict__ pooled,   // [300][83][128]
        const float* __restrict__ w1T,      // [300][83][100]
        const float* __restrict__ fc1b,     // [300][100]
        const float* __restrict__ g2, const float* __restrict__ b2,
        const float* __restrict__ m2, const float* __restrict__ v2,
        const float* __restrict__ fc2w,     // [300][100]
        const float* __restrict__ fc2b,     // [300]
        const float* __restrict__ g3, const float* __restrict__ b3,
        const float* __restrict__ m3, const float* __restrict__ v3,
        float* __restrict__ sout)           // [300][128]
{
    __shared__ float sRed[2][16];
    const int id = blockIdx.x;              // bc*304 + n
    const int bc = id / 304;
    const int n  = id - bc * 304;
    if (n >= 300) return;
    const int tid  = threadIdx.x;
    const int lane = tid & 63;
    const int hw   = tid >> 6;              // 0..1
    const int lc   = (lane < 50) ? lane : 49;
    const int h    = hw * 50 + lc;          // clamped
    const int b0   = bc * 16;

    const float* wp = w1T + (size_t)n * 8300 + h;          // per-lane
    const float* pp = pooled + (size_t)n * 83 * 128 + b0;  // uniform

    float acc[16];
    #pragma unroll
    for (int i = 0; i < 16; ++i) acc[i] = 0.f;

    #pragma unroll 4
    for (int p = 0; p < 83; ++p) {
        const float wv = wp[p * 100];                      // coalesced vector
        const float4 s0 = *reinterpret_cast<const float4*>(pp + p * 128 + 0);
        const float4 s1 = *reinterpret_cast<const float4*>(pp + p * 128 + 4);
        const float4 s2 = *reinterpret_cast<const float4*>(pp + p * 128 + 8);
        const float4 s3 = *reinterpret_cast<const float4*>(pp + p * 128 + 12);
        acc[ 0] = fmaf(s0.x, wv, acc[ 0]);  acc[ 1] = fmaf(s0.y, wv, acc[ 1]);
        acc[ 2] = fmaf(s0.z, wv, acc[ 2]);  acc[ 3] = fmaf(s0.w, wv, acc[ 3]);
        acc[ 4] = fmaf(s1.x, wv, acc[ 4]);  acc[ 5] = fmaf(s1.y, wv, acc[ 5]);
        acc[ 6] = fmaf(s1.z, wv, acc[ 6]);  acc[ 7] = fmaf(s1.w, wv, acc[ 7]);
        acc[ 8] = fmaf(s2.x, wv, acc[ 8]);  acc[ 9] = fmaf(s2.y, wv, acc[ 9]);
        acc[10] = fmaf(s2.z, wv, acc[10]);  acc[11] = fmaf(s2.w, wv, acc[11]);
        acc[12] = fmaf(s3.x, wv, acc[12]);  acc[13] = fmaf(s3.y, wv, acc[13]);
        acc[14] = fmaf(s3.z, wv, acc[14]);  acc[15] = fmaf(s3.w, wv, acc[15]);
    }

    // bn2 + relu + fc2 partials; inactive lanes (lane>=50) masked via w2=0
    const int hi = n * 100 + h;
    const float A2  = g2[hi] * rsqrtf(v2[hi] + EPS_);
    const float C2  = fmaf(A2, fc1b[hi] - m2[hi], b2[hi]);
    const float w2m = (lane < 50) ? fc2w[hi] : 0.f;

    float part[16];
    #pragma unroll
    for (int i = 0; i < 16; ++i)
        part[i] = fmaxf(fmaf(A2, acc[i], C2), 0.f) * w2m;

    #pragma unroll
    for (int off = 32; off > 0; off >>= 1)
        #pragma unroll
        for (int i = 0; i < 16; ++i)
            part[i] += __shfl_xor(part[i], off, 64);

    if (lane == 0) {
        #pragma unroll
        for (int i = 0; i < 16; ++i) sRed[hw][i] = part[i];
    }
    __syncthreads();
    if (tid < 16) {
        float s = sRed[0][tid] + sRed[1][tid] + fc2b[n];
        const float A3 = g3[n] * rsqrtf(v3[n] + EPS_);
        const float z = fmaf(A3, s - m3[n], b3[n]);
        sout[n * 128 + b0 + tid] = fmaxf(z, 0.f);
    }
}

// ---------------------------------------------------------------------------
// kC: out[b,c] = sum_n sout[n][b] * fw[c][n] + fb[c].  grid 128 x 64.
// ---------------------------------------------------------------------------
__global__ __launch_bounds__(64) void kC(
        const float* __restrict__ sout,     // [300][128]
        const float* __restrict__ fw,       // [2][300]
        const float* __restrict__ fb,
        float* __restrict__ out)            // [128][2]
{
    const int b = blockIdx.x, t = threadIdx.x;
    float a0 = 0.f, a1 = 0.f;
    for (int nn = t; nn < 300; nn += 64) {
        const float v = sout[nn * 128 + b];
        a0 = fmaf(v, fw[nn], a0);
        a1 = fmaf(v, fw[300 + nn], a1);
    }
    #pragma unroll
    for (int off = 32; off > 0; off >>= 1) {
        a0 += __shfl_xor(a0, off, 64);
        a1 += __shfl_xor(a1, off, 64);
    }
    if (t == 0) {
        out[b * 2 + 0] = a0 + fb[0];
        out[b * 2 + 1] = a1 + fb[1];
    }
}

extern "C" void kernel_launch(void* const* d_in, const int* in_sizes, int n_in,
                              void* d_out, int out_size, void* d_ws, size_t ws_size,
                              hipStream_t stream) {
    const float* x      = (const float*)d_in[0];
    const float* conv_w = (const float*)d_in[1];
    const float* conv_b = (const float*)d_in[2];
    const float* g1 = (const float*)d_in[3];
    const float* b1 = (const float*)d_in[4];
    const float* m1 = (const float*)d_in[5];
    const float* v1 = (const float*)d_in[6];
    const float* fc1_w = (const float*)d_in[7];
    const float* fc1_b = (const float*)d_in[8];
    const float* g2 = (const float*)d_in[9];
    const float* b2 = (const float*)d_in[10];
    const float* m2 = (const float*)d_in[11];
    const float* v2 = (const float*)d_in[12];
    const float* fc2_w = (const float*)d_in[13];
    const float* fc2_b = (const float*)d_in[14];
    const float* g3 = (const float*)d_in[15];
    const float* b3 = (const float*)d_in[16];
    const float* m3 = (const float*)d_in[17];
    const float* v3 = (const float*)d_in[18];
    const float* fw = (const float*)d_in[19];
    const float* fb = (const float*)d_in[20];
    float* out = (float*)d_out;

    float* pooled = (float*)d_ws;                        // 300*83*128 = 3187200
    float* w1T    = pooled + (size_t)300 * 83 * 128;     // 300*8300   = 2490000
    float* cwT    = w1T + (size_t)300 * 8300;            // 76*300     = 22800
    float* sout   = cwT + 22800;                         // 300*128    = 38400
    // total ws: ~23 MB

    kP<<<301, 256, 0, stream>>>(fc1_w, conv_w, w1T, cwT);
    kA<<<5120, 64, 0, stream>>>(x, cwT, conv_b, g1, b1, m1, v1, pooled);
    kB<<<2432, 128, 0, stream>>>(pooled, w1T, fc1_b, g2, b2, m2, v2,
                                 fc2_w, fc2_b, g3, b3, m3, v3, sout);
    kC<<<128, 64, 0, stream>>>(sout, fw, fb, out);
}

// Round 6
// 195.646 us; speedup vs baseline: 1.1973x; 1.0167x over previous
//
#include <hip/hip_runtime.h>
#include <math.h>

// ExplaiNN fused forward: B=128, N=300, L=600, K=19, C1=100, PS=7
// LC=582, LP=83, NC=2
#define EPS_ 1e-5f

// ---------------------------------------------------------------------------
// kP: transposes. Blocks 0..299: fc1_w[n][h][p] -> w1T[n][p][h] (per-n LDS
// transpose, pad 101 -> conflict-free). Block 300: conv_w[n][c*19+k] ->
// cwT[c*19+k][n] (91 KB LDS stage).
// ---------------------------------------------------------------------------
__global__ __launch_bounds__(256) void kP(const float* __restrict__ fc1w,
                                          const float* __restrict__ conv_w,
                                          float* __restrict__ w1T,
                                          float* __restrict__ cwT) {
    __shared__ float sm[22800];
    const int blk = blockIdx.x, tid = threadIdx.x;
    if (blk < 300) {
        for (int i = tid; i < 8300; i += 256) {
            const int h = i / 83, p = i - h * 83;
            sm[p * 101 + h] = fc1w[(size_t)blk * 8300 + i];
        }
        __syncthreads();
        for (int i = tid; i < 8300; i += 256) {
            const int p = i / 100, h = i - p * 100;
            w1T[(size_t)blk * 8300 + i] = sm[p * 101 + h];
        }
    } else {
        for (int i = tid; i < 22800; i += 256) sm[i] = conv_w[i];
        __syncthreads();
        for (int i = tid; i < 22800; i += 256) {
            const int k = i / 300, n = i - k * 300;
            cwT[i] = sm[n * 76 + k];
        }
    }
}

// ---------------------------------------------------------------------------
// kA: conv1d(4ch,K=19) + bias + bn1 + exp + maxpool(7,7).
// grid 5120 x 64: block id = b*40 + ng*8 + pc  (40%8==0 -> all b of one
// (ng,pc) group land on the SAME XCD -> pooled lines assemble in local L2).
// lane = n. Weights PER-LANE in VGPRs (76 floats) -- __launch_bounds__(64,4)
// caps occupancy at 4 waves/EU so the allocator gets ~128 VGPRs and KEEPS
// them resident (R5's 48-VGPR allocation rematerialized the weight loads
// inside the p-loop: +760 VMEM/p). x is wave-uniform -> s_load; inner loop
// is pure v_fmac_f32 v,s,v. Store pooled[n][p][b] per-lane scatter.
// ---------------------------------------------------------------------------
__global__ __launch_bounds__(64, 4) void kA(
        const float* __restrict__ x,        // [128][4][600]
        const float* __restrict__ cwT,      // [76][300]
        const float* __restrict__ conv_b,
        const float* __restrict__ g1, const float* __restrict__ b1,
        const float* __restrict__ m1, const float* __restrict__ v1,
        float* __restrict__ pooled)         // [300][83][128]
{
    const int id  = blockIdx.x;             // 0..5119
    const int b   = id / 40;
    const int sub = id - b * 40;
    const int ng  = sub >> 3;
    const int pc  = sub & 7;
    const int p0  = (pc * 83) >> 3;
    const int p1  = ((pc + 1) * 83) >> 3;   // chunks of 10/11
    const int lane = threadIdx.x;
    const int n   = ng * 64 + lane;
    const int nc  = (n < 300) ? n : 299;

    // per-lane weights: 76 coalesced loads, resident for the whole wave
    float w[4][19];
    #pragma unroll
    for (int c = 0; c < 4; ++c)
        #pragma unroll
        for (int k = 0; k < 19; ++k)
            w[c][k] = cwT[(c * 19 + k) * 300 + nc];

    const float A1 = g1[nc] * rsqrtf(v1[nc] + EPS_);
    const float B1 = fmaf(A1, conv_b[nc] - m1[nc], b1[nc]);

    const float* xb = x + b * 2400;         // wave-uniform base

    for (int p = p0; p < p1; ++p) {
        const int t0 = 7 * p;
        float acc[7];
        #pragma unroll
        for (int q = 0; q < 7; ++q) acc[q] = 0.f;

        #pragma unroll
        for (int c = 0; c < 4; ++c) {
            const float* xc = xb + c * 600 + t0;   // uniform -> s_load
            float xv[25];
            #pragma unroll
            for (int j = 0; j < 25; ++j) xv[j] = xc[j];
            #pragma unroll
            for (int k = 0; k < 19; ++k) {
                const float wv = w[c][k];
                #pragma unroll
                for (int q = 0; q < 7; ++q)
                    acc[q] = fmaf(xv[k + q], wv, acc[q]);   // v,s,v
            }
        }
        float mx = -INFINITY;               // exp monotone: max before exp
        #pragma unroll
        for (int q = 0; q < 7; ++q) mx = fmaxf(mx, fmaf(A1, acc[q], B1));
        if (n < 300)
            pooled[((size_t)n * 83 + p) * 128 + b] = __expf(mx);
    }
}

// ---------------------------------------------------------------------------
// kB: fc1(K=83) + bn2 + relu + fc2 + bn3 + relu.
// grid 2432 x 128: id = bc*304 + n (304%8==0 -> all 8 b-chunks of one n on
// the same XCD -> w1T L2-resident). 2 waves: h = hw*50 + lane (lane<50).
// lane = h: w1T loads coalesced VECTOR; pooled (16 b) via aligned
// s_load_dwordx4. acc[16] per lane; fc2 = 64-lane butterfly per acc.
// ---------------------------------------------------------------------------
__global__ __launch_bounds__(128, 6) void kB(
        const float* __restrict__ pooled,   // [300][83][128]
        const float* __restrict__ w1T,      // [300][83][100]
        const float* __restrict__ fc1b,     // [300][100]
        const float* __restrict__ g2, const float* __restrict__ b2,
        const float* __restrict__ m2, const float* __restrict__ v2,
        const float* __restrict__ fc2w,     // [300][100]
        const float* __restrict__ fc2b,     // [300]
        const float* __restrict__ g3, const float* __restrict__ b3,
        const float* __restrict__ m3, const float* __restrict__ v3,
        float* __restrict__ sout)           // [300][128]
{
    __shared__ float sRed[2][16];
    const int id = blockIdx.x;              // bc*304 + n
    const int bc = id / 304;
    const int n  = id - bc * 304;
    if (n >= 300) return;
    const int tid  = threadIdx.x;
    const int lane = tid & 63;
    const int hw   = tid >> 6;              // 0..1
    const int lc   = (lane < 50) ? lane : 49;
    const int h    = hw * 50 + lc;          // clamped
    const int b0   = bc * 16;

    const float* wp = w1T + (size_t)n * 8300 + h;          // per-lane
    const float* pp = pooled + (size_t)n * 83 * 128 + b0;  // uniform

    float acc[16];
    #pragma unroll
    for (int i = 0; i < 16; ++i) acc[i] = 0.f;

    #pragma unroll 4
    for (int p = 0; p < 83; ++p) {
        const float wv = wp[p * 100];                      // coalesced vector
        const float4 s0 = *reinterpret_cast<const float4*>(pp + p * 128 + 0);
        const float4 s1 = *reinterpret_cast<const float4*>(pp + p * 128 + 4);
        const float4 s2 = *reinterpret_cast<const float4*>(pp + p * 128 + 8);
        const float4 s3 = *reinterpret_cast<const float4*>(pp + p * 128 + 12);
        acc[ 0] = fmaf(s0.x, wv, acc[ 0]);  acc[ 1] = fmaf(s0.y, wv, acc[ 1]);
        acc[ 2] = fmaf(s0.z, wv, acc[ 2]);  acc[ 3] = fmaf(s0.w, wv, acc[ 3]);
        acc[ 4] = fmaf(s1.x, wv, acc[ 4]);  acc[ 5] = fmaf(s1.y, wv, acc[ 5]);
        acc[ 6] = fmaf(s1.z, wv, acc[ 6]);  acc[ 7] = fmaf(s1.w, wv, acc[ 7]);
        acc[ 8] = fmaf(s2.x, wv, acc[ 8]);  acc[ 9] = fmaf(s2.y, wv, acc[ 9]);
        acc[10] = fmaf(s2.z, wv, acc[10]);  acc[11] = fmaf(s2.w, wv, acc[11]);
        acc[12] = fmaf(s3.x, wv, acc[12]);  acc[13] = fmaf(s3.y, wv, acc[13]);
        acc[14] = fmaf(s3.z, wv, acc[14]);  acc[15] = fmaf(s3.w, wv, acc[15]);
    }

    const int hi = n * 100 + h;
    const float A2  = g2[hi] * rsqrtf(v2[hi] + EPS_);
    const float C2  = fmaf(A2, fc1b[hi] - m2[hi], b2[hi]);
    const float w2m = (lane < 50) ? fc2w[hi] : 0.f;

    float part[16];
    #pragma unroll
    for (int i = 0; i < 16; ++i)
        part[i] = fmaxf(fmaf(A2, acc[i], C2), 0.f) * w2m;

    #pragma unroll
    for (int off = 32; off > 0; off >>= 1)
        #pragma unroll
        for (int i = 0; i < 16; ++i)
            part[i] += __shfl_xor(part[i], off, 64);

    if (lane == 0) {
        #pragma unroll
        for (int i = 0; i < 16; ++i) sRed[hw][i] = part[i];
    }
    __syncthreads();
    if (tid < 16) {
        float s = sRed[0][tid] + sRed[1][tid] + fc2b[n];
        const float A3 = g3[n] * rsqrtf(v3[n] + EPS_);
        const float z = fmaf(A3, s - m3[n], b3[n]);
        sout[n * 128 + b0 + tid] = fmaxf(z, 0.f);
    }
}

// ---------------------------------------------------------------------------
// kC: out[b,c] = sum_n sout[n][b] * fw[c][n] + fb[c].  grid 128 x 64.
// ---------------------------------------------------------------------------
__global__ __launch_bounds__(64) void kC(
        const float* __restrict__ sout,     // [300][128]
        const float* __restrict__ fw,       // [2][300]
        const float* __restrict__ fb,
        float* __restrict__ out)            // [128][2]
{
    const int b = blockIdx.x, t = threadIdx.x;
    float a0 = 0.f, a1 = 0.f;
    for (int nn = t; nn < 300; nn += 64) {
        const float v = sout[nn * 128 + b];
        a0 = fmaf(v, fw[nn], a0);
        a1 = fmaf(v, fw[300 + nn], a1);
    }
    #pragma unroll
    for (int off = 32; off > 0; off >>= 1) {
        a0 += __shfl_xor(a0, off, 64);
        a1 += __shfl_xor(a1, off, 64);
    }
    if (t == 0) {
        out[b * 2 + 0] = a0 + fb[0];
        out[b * 2 + 1] = a1 + fb[1];
    }
}

extern "C" void kernel_launch(void* const* d_in, const int* in_sizes, int n_in,
                              void* d_out, int out_size, void* d_ws, size_t ws_size,
                              hipStream_t stream) {
    const float* x      = (const float*)d_in[0];
    const float* conv_w = (const float*)d_in[1];
    const float* conv_b = (const float*)d_in[2];
    const float* g1 = (const float*)d_in[3];
    const float* b1 = (const float*)d_in[4];
    const float* m1 = (const float*)d_in[5];
    const float* v1 = (const float*)d_in[6];
    const float* fc1_w = (const float*)d_in[7];
    const float* fc1_b = (const float*)d_in[8];
    const float* g2 = (const float*)d_in[9];
    const float* b2 = (const float*)d_in[10];
    const float* m2 = (const float*)d_in[11];
    const float* v2 = (const float*)d_in[12];
    const float* fc2_w = (const float*)d_in[13];
    const float* fc2_b = (const float*)d_in[14];
    const float* g3 = (const float*)d_in[15];
    const float* b3 = (const float*)d_in[16];
    const float* m3 = (const float*)d_in[17];
    const float* v3 = (const float*)d_in[18];
    const float* fw = (const float*)d_in[19];
    const float* fb = (const float*)d_in[20];
    float* out = (float*)d_out;

    float* pooled = (float*)d_ws;                        // 300*83*128 = 3187200
    float* w1T    = pooled + (size_t)300 * 83 * 128;     // 300*8300   = 2490000
    float* cwT    = w1T + (size_t)300 * 8300;            // 76*300     = 22800
    float* sout   = cwT + 22800;                         // 300*128    = 38400
    // total ws: ~23 MB

    kP<<<301, 256, 0, stream>>>(fc1_w, conv_w, w1T, cwT);
    kA<<<5120, 64, 0, stream>>>(x, cwT, conv_b, g1, b1, m1, v1, pooled);
    kB<<<2432, 128, 0, stream>>>(pooled, w1T, fc1_b, g2, b2, m2, v2,
                                 fc2_w, fc2_b, g3, b3, m3, v3, sout);
    kC<<<128, 64, 0, stream>>>(sout, fw, fb, out);
}

// Round 7
// 189.793 us; speedup vs baseline: 1.2342x; 1.0308x over previous
//
#include <hip/hip_runtime.h>
#include <math.h>

// ExplaiNN fused forward: B=128, N=300, L=600, K=19, C1=100, PS=7
// LC=582, LP=83, NC=2
#define EPS_ 1e-5f

// ---------------------------------------------------------------------------
// kP: transposes. Blocks 0..299: fc1_w[n][h][p] -> w1T[n][p][h] (per-n LDS
// transpose, pad 101 -> conflict-free). Block 300: conv_w[n][c*19+k] ->
// cwT[c*19+k][n] (91 KB LDS stage).
// ---------------------------------------------------------------------------
__global__ __launch_bounds__(256) void kP(const float* __restrict__ fc1w,
                                          const float* __restrict__ conv_w,
                                          float* __restrict__ w1T,
                                          float* __restrict__ cwT) {
    __shared__ float sm[22800];
    const int blk = blockIdx.x, tid = threadIdx.x;
    if (blk < 300) {
        for (int i = tid; i < 8300; i += 256) {
            const int h = i / 83, p = i - h * 83;
            sm[p * 101 + h] = fc1w[(size_t)blk * 8300 + i];
        }
        __syncthreads();
        for (int i = tid; i < 8300; i += 256) {
            const int p = i / 100, h = i - p * 100;
            w1T[(size_t)blk * 8300 + i] = sm[p * 101 + h];
        }
    } else {
        for (int i = tid; i < 22800; i += 256) sm[i] = conv_w[i];
        __syncthreads();
        for (int i = tid; i < 22800; i += 256) {
            const int k = i / 300, n = i - k * 300;
            cwT[i] = sm[n * 76 + k];
        }
    }
}

// ---------------------------------------------------------------------------
// kA: conv1d(4ch,K=19) + bias + bn1 + exp + maxpool(7,7).
// LOOP-INTERCHANGED: persistent state = acc[4p x 7q] (28 VGPR, can't remat);
// each weight is loaded ONCE and lives for one k-iteration (28 FMAs) -> the
// allocator's occupancy-minimizing heuristic has nothing to rematerialize
// (R5/R6: 76-wide weight array got reloaded per p, 44-48 VGPR, 67us).
// grid 128*112 x 64: id = b*112 + sub (112%8==0 -> all b of one (ng,pc)
// group on the same XCD for pooled line assembly). sub = ng*21 + pc < 105.
// lane = n. x window (46 floats/channel) wave-uniform -> s_loads.
// Task = 4 pooled outputs; p0 clamped to 79 so x reads stay in-bounds
// (p=79 computed by two tasks, same value -> benign).
// ---------------------------------------------------------------------------
__global__ __launch_bounds__(64) void kA(
        const float* __restrict__ x,        // [128][4][600]
        const float* __restrict__ cwT,      // [76][300]
        const float* __restrict__ conv_b,
        const float* __restrict__ g1, const float* __restrict__ b1,
        const float* __restrict__ m1, const float* __restrict__ v1,
        float* __restrict__ pooled)         // [300][83][128]
{
    const int id  = blockIdx.x;             // b*112 + sub
    const int b   = id / 112;
    const int sub = id - b * 112;
    if (sub >= 105) return;
    const int ng  = sub / 21;
    const int pc  = sub - ng * 21;
    const int p0c = pc * 4;
    const int p0  = (p0c > 79) ? 79 : p0c;
    const int lane = threadIdx.x;
    const int n   = ng * 64 + lane;
    const int nc  = (n < 300) ? n : 299;

    float acc[28];
    #pragma unroll
    for (int i = 0; i < 28; ++i) acc[i] = 0.f;

    #pragma unroll 1
    for (int c = 0; c < 4; ++c) {
        const float* xc = x + b * 2400 + c * 600 + 7 * p0;  // uniform -> s_load
        float xw[46];
        #pragma unroll
        for (int j = 0; j < 46; ++j) xw[j] = xc[j];
        const float* wc = cwT + c * 19 * 300 + nc;          // per-lane
        #pragma unroll
        for (int k = 0; k < 19; ++k) {
            const float wv = wc[k * 300];   // one load, 28 FMAs, then dead
            #pragma unroll
            for (int p = 0; p < 4; ++p)
                #pragma unroll
                for (int q = 0; q < 7; ++q)
                    acc[p * 7 + q] = fmaf(xw[7 * p + q + k], wv, acc[p * 7 + q]);
        }
    }

    const float A1 = g1[nc] * rsqrtf(v1[nc] + EPS_);
    const float B1 = fmaf(A1, conv_b[nc] - m1[nc], b1[nc]);
    if (n < 300) {
        float* op = pooled + ((size_t)n * 83 + p0) * 128 + b;
        #pragma unroll
        for (int p = 0; p < 4; ++p) {
            float mx = -INFINITY;           // exp monotone: max before exp
            #pragma unroll
            for (int q = 0; q < 7; ++q)
                mx = fmaxf(mx, fmaf(A1, acc[p * 7 + q], B1));
            op[p * 128] = __expf(mx);
        }
    }
}

// ---------------------------------------------------------------------------
// kB: fc1(K=83) + bn2 + relu + fc2 + bn3 + relu.
// grid 608 x 128: id = bh*304 + n (304%8==0 -> both b-halves of one n on the
// same XCD -> shared w1T in local L2). 2 waves: hh = wave id (readfirstlane
// -> provably uniform -> weight/param loads are s_load, NOT the R6 scheme
// where 12.7MB of pooled streamed through the scalar cache). lane = b:
// pooled = 1 coalesced vector load per p. acc[50]/lane; thread owns all its
// 50 h -> fc2 partial in-thread; 2x64 LDS combine.
// ---------------------------------------------------------------------------
__global__ __launch_bounds__(128) void kB(
        const float* __restrict__ pooled,   // [300][83][128]
        const float* __restrict__ w1T,      // [300][83][100]
        const float* __restrict__ fc1b,     // [300][100]
        const float* __restrict__ g2, const float* __restrict__ b2,
        const float* __restrict__ m2, const float* __restrict__ v2,
        const float* __restrict__ fc2w,     // [300][100]
        const float* __restrict__ fc2b,     // [300]
        const float* __restrict__ g3, const float* __restrict__ b3,
        const float* __restrict__ m3, const float* __restrict__ v3,
        float* __restrict__ sout)           // [300][128]
{
    __shared__ float sRed[2][64];
    const int id = blockIdx.x;              // bh*304 + n
    const int bh = id / 304;
    const int n  = id - bh * 304;
    if (n >= 300) return;
    const int tid  = threadIdx.x;
    const int lane = tid & 63;
    const int hh   = __builtin_amdgcn_readfirstlane(tid >> 6);  // uniform!
    const int h0   = hh * 50;
    const int bb   = bh * 64 + lane;

    const float* pp = pooled + (size_t)n * 83 * 128 + bb;   // per-lane
    const float* wp = w1T + (size_t)n * 8300 + h0;          // uniform

    float acc[50];
    #pragma unroll
    for (int j = 0; j < 50; ++j) acc[j] = 0.f;

    #pragma unroll 2
    for (int p = 0; p < 83; ++p) {
        const float pv = pp[p * 128];                       // coalesced vector
        #pragma unroll
        for (int j = 0; j < 50; ++j)
            acc[j] = fmaf(pv, wp[p * 100 + j], acc[j]);     // v,s,v
    }

    // bn2 + relu + fc2 partial: this thread owns h = h0..h0+49 for batch bb
    const int base = n * 100 + h0;                          // uniform
    float part = 0.f;
    #pragma unroll
    for (int j = 0; j < 50; ++j) {
        const float A2 = g2[base + j] * rsqrtf(v2[base + j] + EPS_);
        const float C2 = fmaf(A2, fc1b[base + j] - m2[base + j], b2[base + j]);
        const float act = fmaxf(fmaf(A2, acc[j], C2), 0.f);
        part = fmaf(act, fc2w[base + j], part);
    }
    sRed[hh][lane] = part;
    __syncthreads();
    if (tid < 64) {
        float s = sRed[0][tid] + sRed[1][tid] + fc2b[n];
        const float A3 = g3[n] * rsqrtf(v3[n] + EPS_);
        const float z = fmaf(A3, s - m3[n], b3[n]);
        sout[n * 128 + bh * 64 + tid] = fmaxf(z, 0.f);
    }
}

// ---------------------------------------------------------------------------
// kC: out[b,c] = sum_n sout[n][b] * fw[c][n] + fb[c].  grid 128 x 64.
// ---------------------------------------------------------------------------
__global__ __launch_bounds__(64) void kC(
        const float* __restrict__ sout,     // [300][128]
        const float* __restrict__ fw,       // [2][300]
        const float* __restrict__ fb,
        float* __restrict__ out)            // [128][2]
{
    const int b = blockIdx.x, t = threadIdx.x;
    float a0 = 0.f, a1 = 0.f;
    for (int nn = t; nn < 300; nn += 64) {
        const float v = sout[nn * 128 + b];
        a0 = fmaf(v, fw[nn], a0);
        a1 = fmaf(v, fw[300 + nn], a1);
    }
    #pragma unroll
    for (int off = 32; off > 0; off >>= 1) {
        a0 += __shfl_xor(a0, off, 64);
        a1 += __shfl_xor(a1, off, 64);
    }
    if (t == 0) {
        out[b * 2 + 0] = a0 + fb[0];
        out[b * 2 + 1] = a1 + fb[1];
    }
}

extern "C" void kernel_launch(void* const* d_in, const int* in_sizes, int n_in,
                              void* d_out, int out_size, void* d_ws, size_t ws_size,
                              hipStream_t stream) {
    const float* x      = (const float*)d_in[0];
    const float* conv_w = (const float*)d_in[1];
    const float* conv_b = (const float*)d_in[2];
    const float* g1 = (const float*)d_in[3];
    const float* b1 = (const float*)d_in[4];
    const float* m1 = (const float*)d_in[5];
    const float* v1 = (const float*)d_in[6];
    const float* fc1_w = (const float*)d_in[7];
    const float* fc1_b = (const float*)d_in[8];
    const float* g2 = (const float*)d_in[9];
    const float* b2 = (const float*)d_in[10];
    const float* m2 = (const float*)d_in[11];
    const float* v2 = (const float*)d_in[12];
    const float* fc2_w = (const float*)d_in[13];
    const float* fc2_b = (const float*)d_in[14];
    const float* g3 = (const float*)d_in[15];
    const float* b3 = (const float*)d_in[16];
    const float* m3 = (const float*)d_in[17];
    const float* v3 = (const float*)d_in[18];
    const float* fw = (const float*)d_in[19];
    const float* fb = (const float*)d_in[20];
    float* out = (float*)d_out;

    float* pooled = (float*)d_ws;                        // 300*83*128 = 3187200
    float* w1T    = pooled + (size_t)300 * 83 * 128;     // 300*8300   = 2490000
    float* cwT    = w1T + (size_t)300 * 8300;            // 76*300     = 22800
    float* sout   = cwT + 22800;                         // 300*128    = 38400
    // total ws: ~23 MB

    kP<<<301, 256, 0, stream>>>(fc1_w, conv_w, w1T, cwT);
    kA<<<128 * 112, 64, 0, stream>>>(x, cwT, conv_b, g1, b1, m1, v1, pooled);
    kB<<<608, 128, 0, stream>>>(pooled, w1T, fc1_b, g2, b2, m2, v2,
                                fc2_w, fc2_b, g3, b3, m3, v3, sout);
    kC<<<128, 64, 0, stream>>>(sout, fw, fb, out);
}